// Round 1
// baseline (1138.888 us; speedup 1.0000x reference)
//
#include <hip/hip_runtime.h>

#define BB 1024
#define SS 2048
#define DD 64
#define HH 4
#define HDIM 16
#define NT 256

__global__ __launch_bounds__(NT, 4)
void actformer_kernel(
    const float* __restrict__ query,    // [B,1,D]
    const float* __restrict__ scratch,  // [B,S,D]
    const float* __restrict__ wq,       // [D,D]
    const float* __restrict__ wk,       // [D,D]
    const float* __restrict__ wv,       // [D,D]
    const float* __restrict__ bq,       // [D]
    const float* __restrict__ bk,       // [D] (constant shift -> softmax invariant; unused)
    const float* __restrict__ bv,       // [D]
    const float* __restrict__ wo,       // [D,D]
    const float* __restrict__ bo,       // [D]
    const float* __restrict__ w_write,  // [D,D]
    const float* __restrict__ b_write,  // [D]
    const float* __restrict__ w_a1,     // [128,D]
    const float* __restrict__ b_a1,     // [128]
    const float* __restrict__ w_a2,     // [S,128]
    const float* __restrict__ b_a2,     // [S]
    float* __restrict__ out)            // [B,S,D]
{
    const int b   = blockIdx.x;
    const int tid = threadIdx.x;
    const int grp = tid >> 4;   // 0..15 : 16-lane row group
    const int lan = tid & 15;   // 0..15 : lane within group, covers cols lan*4..lan*4+3

    __shared__ float s_qf[DD];
    __shared__ float s_g[HH][DD];
    __shared__ float s_red[16][HH][DD];   // 16 KB partial ctx accumulators
    __shared__ float s_redd[16][HH];
    __shared__ float s_cb[HH][DD];
    __shared__ float s_invden[HH];
    __shared__ float s_ctx[DD];
    __shared__ float s_value[DD];
    __shared__ float s_h1[128];
    __shared__ float s_wval[DD];
    __shared__ float s_p[SS];             // 8 KB: logits -> exp weights
    __shared__ float s_rtmp[4];

    const float* x0 = scratch + (size_t)b * SS * DD;

    // ---- q = query @ wq.T + bq  (threads 0..63)
    if (tid < DD) {
        float acc = bq[tid];
        const float* qrow = query + (size_t)b * DD;
        const float* wrow = wq + tid * DD;
        #pragma unroll
        for (int c = 0; c < DD; c += 4) {
            float4 qv = *(const float4*)(qrow + c);
            float4 wv4 = *(const float4*)(wrow + c);
            acc += qv.x*wv4.x + qv.y*wv4.y + qv.z*wv4.z + qv.w*wv4.w;
        }
        s_qf[tid] = acc;
    }
    __syncthreads();

    // ---- g[h][c] = (1/sqrt(HD)) * sum_j qf[h*16+j] * wk[(h*16+j)*64 + c]
    {
        int h = tid >> 6;
        int c = tid & 63;
        float acc = 0.f;
        #pragma unroll
        for (int j = 0; j < HDIM; ++j)
            acc += s_qf[h*HDIM + j] * wk[(h*HDIM + j)*DD + c];
        s_g[h][c] = acc * 0.25f;
    }
    __syncthreads();

    // per-lane g fragments in registers
    float gf[HH][4];
    #pragma unroll
    for (int h = 0; h < HH; ++h) {
        float4 t = *(const float4*)&s_g[h][lan*4];
        gf[h][0]=t.x; gf[h][1]=t.y; gf[h][2]=t.z; gf[h][3]=t.w;
    }

    // ---- Phase 1: single streaming pass; online exp accumulation (scores are O(1), no max needed)
    float cacc[HH][4];
    float dacc[HH];
    #pragma unroll
    for (int h = 0; h < HH; ++h) {
        dacc[h] = 0.f;
        cacc[h][0]=0.f; cacc[h][1]=0.f; cacc[h][2]=0.f; cacc[h][3]=0.f;
    }

    for (int it = 0; it < SS/16; ++it) {
        int s = it*16 + grp;
        float4 xv = *(const float4*)(x0 + (size_t)s*DD + lan*4);
        float sc[HH];
        #pragma unroll
        for (int h = 0; h < HH; ++h)
            sc[h] = gf[h][0]*xv.x + gf[h][1]*xv.y + gf[h][2]*xv.z + gf[h][3]*xv.w;
        #pragma unroll
        for (int m = 1; m < 16; m <<= 1) {
            #pragma unroll
            for (int h = 0; h < HH; ++h)
                sc[h] += __shfl_xor(sc[h], m, 64);
        }
        #pragma unroll
        for (int h = 0; h < HH; ++h) {
            float w = __expf(sc[h]);
            cacc[h][0] += w*xv.x; cacc[h][1] += w*xv.y;
            cacc[h][2] += w*xv.z; cacc[h][3] += w*xv.w;
            dacc[h] += w;
        }
    }

    // cross-group reduction of ctx accumulators
    #pragma unroll
    for (int h = 0; h < HH; ++h) {
        float4 t; t.x=cacc[h][0]; t.y=cacc[h][1]; t.z=cacc[h][2]; t.w=cacc[h][3];
        *(float4*)&s_red[grp][h][lan*4] = t;
    }
    if (lan == 0) {
        #pragma unroll
        for (int h = 0; h < HH; ++h) s_redd[grp][h] = dacc[h];
    }
    __syncthreads();
    {
        int h = tid >> 6, c = tid & 63;
        float acc = 0.f;
        #pragma unroll
        for (int g2 = 0; g2 < 16; ++g2) acc += s_red[g2][h][c];
        s_cb[h][c] = acc;
    }
    if (tid < HH) {
        float dsum = 0.f;
        #pragma unroll
        for (int g2 = 0; g2 < 16; ++g2) dsum += s_redd[g2][tid];
        s_invden[tid] = 1.0f / dsum;
    }
    __syncthreads();

    // ---- ctx[d] = wv[d,:]·cb[h]/den + bv[d],  d = h*16+j
    if (tid < DD) {
        int h = tid >> 4;
        float acc = 0.f;
        const float* wrow = wv + tid*DD;
        #pragma unroll 8
        for (int c = 0; c < DD; ++c) acc += wrow[c] * s_cb[h][c];
        s_ctx[tid] = acc * s_invden[h] + bv[tid];
    }
    __syncthreads();

    // ---- value = wo·ctx + bo
    if (tid < DD) {
        float acc = bo[tid];
        const float* wrow = wo + tid*DD;
        #pragma unroll 8
        for (int c = 0; c < DD; ++c) acc += wrow[c] * s_ctx[c];
        s_value[tid] = acc;
    }
    __syncthreads();

    // ---- h1 = relu(w_a1·value + b_a1) ; write_value = w_write·value + b_write
    if (tid < 128) {
        float acc = b_a1[tid];
        const float* wrow = w_a1 + tid*DD;
        #pragma unroll 8
        for (int c = 0; c < DD; ++c) acc += wrow[c] * s_value[c];
        s_h1[tid] = fmaxf(acc, 0.f);
    } else if (tid < 192) {
        int i = tid - 128;
        float acc = b_write[i];
        const float* wrow = w_write + i*DD;
        #pragma unroll 8
        for (int c = 0; c < DD; ++c) acc += wrow[c] * s_value[c];
        s_wval[i] = acc;
    }
    __syncthreads();

    // ---- logits[s] = w_a2[s,:]·h1 + b_a2[s], cooperative 16-lane dot
    float h1r[8];
    {
        float4 ha = *(const float4*)&s_h1[lan*8];
        float4 hb = *(const float4*)&s_h1[lan*8+4];
        h1r[0]=ha.x; h1r[1]=ha.y; h1r[2]=ha.z; h1r[3]=ha.w;
        h1r[4]=hb.x; h1r[5]=hb.y; h1r[6]=hb.z; h1r[7]=hb.w;
    }
    for (int it = 0; it < SS/16; ++it) {
        int s = it*16 + grp;
        const float* wrow = w_a2 + (size_t)s*128 + lan*8;
        float4 wa = *(const float4*)(wrow);
        float4 wb = *(const float4*)(wrow + 4);
        float acc = wa.x*h1r[0] + wa.y*h1r[1] + wa.z*h1r[2] + wa.w*h1r[3]
                  + wb.x*h1r[4] + wb.y*h1r[5] + wb.z*h1r[6] + wb.w*h1r[7];
        #pragma unroll
        for (int m = 1; m < 16; m <<= 1) acc += __shfl_xor(acc, m, 64);
        if (lan == 0) s_p[s] = acc + b_a2[s];
    }
    __syncthreads();

    // ---- softmax over s_p[0..2047]
    float lmax = -1e30f;
    for (int s = tid; s < SS; s += NT) lmax = fmaxf(lmax, s_p[s]);
    #pragma unroll
    for (int m = 1; m < 64; m <<= 1) lmax = fmaxf(lmax, __shfl_xor(lmax, m, 64));
    if ((tid & 63) == 0) s_rtmp[tid >> 6] = lmax;
    __syncthreads();
    float gmax = fmaxf(fmaxf(s_rtmp[0], s_rtmp[1]), fmaxf(s_rtmp[2], s_rtmp[3]));
    __syncthreads();
    float lsum = 0.f;
    for (int s = tid; s < SS; s += NT) {
        float e = __expf(s_p[s] - gmax);
        s_p[s] = e;
        lsum += e;
    }
    #pragma unroll
    for (int m = 1; m < 64; m <<= 1) lsum += __shfl_xor(lsum, m, 64);
    if ((tid & 63) == 0) s_rtmp[tid >> 6] = lsum;
    __syncthreads();
    float inv_z = 1.0f / (s_rtmp[0] + s_rtmp[1] + s_rtmp[2] + s_rtmp[3]);

    // ---- Phase 2: blend  out = x + a*(write_value - x)
    float4 wvv = *(const float4*)&s_wval[lan*4];
    float* o0 = out + (size_t)b * SS * DD;
    for (int it = 0; it < SS/16; ++it) {
        int s = it*16 + grp;
        float a = s_p[s] * inv_z;
        float4 xv = *(const float4*)(x0 + (size_t)s*DD + lan*4);
        float4 o;
        o.x = xv.x + a*(wvv.x - xv.x);
        o.y = xv.y + a*(wvv.y - xv.y);
        o.z = xv.z + a*(wvv.z - xv.z);
        o.w = xv.w + a*(wvv.w - xv.w);
        *(float4*)(o0 + (size_t)s*DD + lan*4) = o;
    }
}

extern "C" void kernel_launch(void* const* d_in, const int* in_sizes, int n_in,
                              void* d_out, int out_size, void* d_ws, size_t ws_size,
                              hipStream_t stream) {
    const float* query   = (const float*)d_in[0];
    const float* scratch = (const float*)d_in[1];
    const float* wq      = (const float*)d_in[2];
    const float* wk      = (const float*)d_in[3];
    const float* wv      = (const float*)d_in[4];
    const float* bq      = (const float*)d_in[5];
    const float* bk      = (const float*)d_in[6];
    const float* bv      = (const float*)d_in[7];
    const float* wo      = (const float*)d_in[8];
    const float* bo      = (const float*)d_in[9];
    const float* w_write = (const float*)d_in[10];
    const float* b_write = (const float*)d_in[11];
    const float* w_a1    = (const float*)d_in[12];
    const float* b_a1    = (const float*)d_in[13];
    const float* w_a2    = (const float*)d_in[14];
    const float* b_a2    = (const float*)d_in[15];
    float* out = (float*)d_out;

    actformer_kernel<<<dim3(BB), dim3(NT), 0, stream>>>(
        query, scratch, wq, wk, wv, bq, bk, bv, wo, bo,
        w_write, b_write, w_a1, b_a1, w_a2, b_a2, out);
}

// Round 2
// 1079.102 us; speedup vs baseline: 1.0554x; 1.0554x over previous
//
#include <hip/hip_runtime.h>

#define BB 1024
#define SS 2048
#define DD 64
#define HH 4
#define HDIM 16
#define NT 512
#define NW (NT/64)   // 8 waves
#define NG (NT/16)   // 32 row-groups

__global__ __launch_bounds__(NT, 8)
void actformer_kernel(
    const float* __restrict__ query,    // [B,1,D]
    const float* __restrict__ scratch,  // [B,S,D]
    const float* __restrict__ wq,       // [D,D]
    const float* __restrict__ wk,       // [D,D]
    const float* __restrict__ wv,       // [D,D]
    const float* __restrict__ bq,       // [D]
    const float* __restrict__ bk,       // [D] constant shift -> softmax invariant; unused
    const float* __restrict__ bv,       // [D]
    const float* __restrict__ wo,       // [D,D]
    const float* __restrict__ bo,       // [D]
    const float* __restrict__ w_write,  // [D,D]
    const float* __restrict__ b_write,  // [D]
    const float* __restrict__ w_a1,     // [128,D]
    const float* __restrict__ b_a1,     // [128]
    const float* __restrict__ w_a2,     // [S,128]
    const float* __restrict__ b_a2,     // [S]
    float* __restrict__ out)            // [B,S,D]
{
    const int b   = blockIdx.x;
    const int tid = threadIdx.x;
    const int grp = tid >> 4;   // 0..31 : 16-lane row group
    const int lan = tid & 15;   // 0..15 : covers cols lan*4..lan*4+3

    __shared__ float s_qf[DD];
    __shared__ float s_g[HH][DD];
    __shared__ float s_red[NW][HH][DD];   // 8 KB: per-wave ctx partials
    __shared__ float s_redd[NW][HH];
    __shared__ float s_cb[HH][DD];
    __shared__ float s_invden[HH];
    __shared__ float s_ctx[DD];
    __shared__ float s_value[DD];
    __shared__ float s_h1[128];
    __shared__ float s_wval[DD];
    __shared__ float s_p[SS];             // 8 KB: logits -> exp weights
    __shared__ float s_rtmp[NW];

    const float* x0 = scratch + (size_t)b * SS * DD;

    // ---- q = query @ wq.T + bq  (threads 0..63)
    if (tid < DD) {
        float acc = bq[tid];
        const float* qrow = query + (size_t)b * DD;
        const float* wrow = wq + tid * DD;
        #pragma unroll
        for (int c = 0; c < DD; c += 4) {
            float4 qv = *(const float4*)(qrow + c);
            float4 wv4 = *(const float4*)(wrow + c);
            acc += qv.x*wv4.x + qv.y*wv4.y + qv.z*wv4.z + qv.w*wv4.w;
        }
        s_qf[tid] = acc;
    }
    __syncthreads();

    // ---- g[h][c] = (1/sqrt(HD)) * sum_j qf[h*16+j] * wk[(h*16+j)*64 + c]
    if (tid < 256) {
        int h = tid >> 6;
        int c = tid & 63;
        float acc = 0.f;
        #pragma unroll
        for (int j = 0; j < HDIM; ++j)
            acc += s_qf[h*HDIM + j] * wk[(h*HDIM + j)*DD + c];
        s_g[h][c] = acc * 0.25f;
    }
    __syncthreads();

    // per-lane g fragments in registers
    float gf[HH][4];
    #pragma unroll
    for (int h = 0; h < HH; ++h) {
        float4 t = *(const float4*)&s_g[h][lan*4];
        gf[h][0]=t.x; gf[h][1]=t.y; gf[h][2]=t.z; gf[h][3]=t.w;
    }

    // ---- Phase 1: single streaming pass; online exp accumulation
    float cacc[HH][4];
    float dacc[HH];
    #pragma unroll
    for (int h = 0; h < HH; ++h) {
        dacc[h] = 0.f;
        cacc[h][0]=0.f; cacc[h][1]=0.f; cacc[h][2]=0.f; cacc[h][3]=0.f;
    }

    #pragma unroll 2
    for (int it = 0; it < SS/NG; ++it) {
        int s = it*NG + grp;
        float4 xv = *(const float4*)(x0 + (size_t)s*DD + lan*4);
        float sc[HH];
        #pragma unroll
        for (int h = 0; h < HH; ++h)
            sc[h] = gf[h][0]*xv.x + gf[h][1]*xv.y + gf[h][2]*xv.z + gf[h][3]*xv.w;
        #pragma unroll
        for (int m = 1; m < 16; m <<= 1) {
            #pragma unroll
            for (int h = 0; h < HH; ++h)
                sc[h] += __shfl_xor(sc[h], m, 64);
        }
        #pragma unroll
        for (int h = 0; h < HH; ++h) {
            float w = __expf(sc[h]);
            cacc[h][0] += w*xv.x; cacc[h][1] += w*xv.y;
            cacc[h][2] += w*xv.z; cacc[h][3] += w*xv.w;
            dacc[h] += w;
        }
    }

    // reduce across the wave's 4 groups in-register (lanes xor 16,32)
    #pragma unroll
    for (int m = 16; m < 64; m <<= 1) {
        #pragma unroll
        for (int h = 0; h < HH; ++h) {
            dacc[h] += __shfl_xor(dacc[h], m, 64);
            #pragma unroll
            for (int j = 0; j < 4; ++j)
                cacc[h][j] += __shfl_xor(cacc[h][j], m, 64);
        }
    }
    {
        int wv_id = tid >> 6;
        int l64   = tid & 63;
        if (l64 < 16) {
            #pragma unroll
            for (int h = 0; h < HH; ++h) {
                float4 t; t.x=cacc[h][0]; t.y=cacc[h][1]; t.z=cacc[h][2]; t.w=cacc[h][3];
                *(float4*)&s_red[wv_id][h][l64*4] = t;
            }
            if (l64 == 0) {
                #pragma unroll
                for (int h = 0; h < HH; ++h) s_redd[wv_id][h] = dacc[h];
            }
        }
    }
    __syncthreads();
    if (tid < 256) {
        int h = tid >> 6, c = tid & 63;
        float acc = 0.f;
        #pragma unroll
        for (int w2 = 0; w2 < NW; ++w2) acc += s_red[w2][h][c];
        s_cb[h][c] = acc;
    }
    if (tid < HH) {
        float dsum = 0.f;
        #pragma unroll
        for (int w2 = 0; w2 < NW; ++w2) dsum += s_redd[w2][tid];
        s_invden[tid] = 1.0f / dsum;
    }
    __syncthreads();

    // ---- ctx[d] = wv[d,:]·cb[h]/den + bv[d],  d = h*16+j
    if (tid < DD) {
        int h = tid >> 4;
        float acc = 0.f;
        const float* wrow = wv + tid*DD;
        #pragma unroll 8
        for (int c = 0; c < DD; ++c) acc += wrow[c] * s_cb[h][c];
        s_ctx[tid] = acc * s_invden[h] + bv[tid];
    }
    __syncthreads();

    // ---- value = wo·ctx + bo
    if (tid < DD) {
        float acc = bo[tid];
        const float* wrow = wo + tid*DD;
        #pragma unroll 8
        for (int c = 0; c < DD; ++c) acc += wrow[c] * s_ctx[c];
        s_value[tid] = acc;
    }
    __syncthreads();

    // ---- h1 = relu(w_a1·value + b_a1) ; write_value = w_write·value + b_write
    if (tid < 128) {
        float acc = b_a1[tid];
        const float* wrow = w_a1 + tid*DD;
        #pragma unroll 8
        for (int c = 0; c < DD; ++c) acc += wrow[c] * s_value[c];
        s_h1[tid] = fmaxf(acc, 0.f);
    } else if (tid < 192) {
        int i = tid - 128;
        float acc = b_write[i];
        const float* wrow = w_write + i*DD;
        #pragma unroll 8
        for (int c = 0; c < DD; ++c) acc += wrow[c] * s_value[c];
        s_wval[i] = acc;
    }
    __syncthreads();

    // ---- logits[s] = w_a2[s,:]·h1 + b_a2[s], cooperative 16-lane dot
    float h1r[8];
    {
        float4 ha = *(const float4*)&s_h1[lan*8];
        float4 hb = *(const float4*)&s_h1[lan*8+4];
        h1r[0]=ha.x; h1r[1]=ha.y; h1r[2]=ha.z; h1r[3]=ha.w;
        h1r[4]=hb.x; h1r[5]=hb.y; h1r[6]=hb.z; h1r[7]=hb.w;
    }
    #pragma unroll 2
    for (int it = 0; it < SS/NG; ++it) {
        int s = it*NG + grp;
        const float* wrow = w_a2 + (size_t)s*128 + lan*8;
        float4 wa = *(const float4*)(wrow);
        float4 wb = *(const float4*)(wrow + 4);
        float acc = wa.x*h1r[0] + wa.y*h1r[1] + wa.z*h1r[2] + wa.w*h1r[3]
                  + wb.x*h1r[4] + wb.y*h1r[5] + wb.z*h1r[6] + wb.w*h1r[7];
        #pragma unroll
        for (int m = 1; m < 16; m <<= 1) acc += __shfl_xor(acc, m, 64);
        if (lan == 0) s_p[s] = acc + b_a2[s];
    }
    __syncthreads();

    // ---- softmax over s_p[0..2047]
    float lmax = -1e30f;
    for (int s = tid; s < SS; s += NT) lmax = fmaxf(lmax, s_p[s]);
    #pragma unroll
    for (int m = 1; m < 64; m <<= 1) lmax = fmaxf(lmax, __shfl_xor(lmax, m, 64));
    if ((tid & 63) == 0) s_rtmp[tid >> 6] = lmax;
    __syncthreads();
    float gmax = s_rtmp[0];
    #pragma unroll
    for (int w2 = 1; w2 < NW; ++w2) gmax = fmaxf(gmax, s_rtmp[w2]);
    __syncthreads();
    float lsum = 0.f;
    for (int s = tid; s < SS; s += NT) {
        float e = __expf(s_p[s] - gmax);
        s_p[s] = e;
        lsum += e;
    }
    #pragma unroll
    for (int m = 1; m < 64; m <<= 1) lsum += __shfl_xor(lsum, m, 64);
    if ((tid & 63) == 0) s_rtmp[tid >> 6] = lsum;
    __syncthreads();
    float zsum = 0.f;
    #pragma unroll
    for (int w2 = 0; w2 < NW; ++w2) zsum += s_rtmp[w2];
    float inv_z = 1.0f / zsum;

    // ---- Phase 2: blend  out = x + a*(write_value - x)
    float4 wvv = *(const float4*)&s_wval[lan*4];
    float* o0 = out + (size_t)b * SS * DD;
    #pragma unroll 2
    for (int it = 0; it < SS/NG; ++it) {
        int s = it*NG + grp;
        float a = s_p[s] * inv_z;
        float4 xv = *(const float4*)(x0 + (size_t)s*DD + lan*4);
        float4 o;
        o.x = xv.x + a*(wvv.x - xv.x);
        o.y = xv.y + a*(wvv.y - xv.y);
        o.z = xv.z + a*(wvv.z - xv.z);
        o.w = xv.w + a*(wvv.w - xv.w);
        *(float4*)(o0 + (size_t)s*DD + lan*4) = o;
    }
}

extern "C" void kernel_launch(void* const* d_in, const int* in_sizes, int n_in,
                              void* d_out, int out_size, void* d_ws, size_t ws_size,
                              hipStream_t stream) {
    const float* query   = (const float*)d_in[0];
    const float* scratch = (const float*)d_in[1];
    const float* wq      = (const float*)d_in[2];
    const float* wk      = (const float*)d_in[3];
    const float* wv      = (const float*)d_in[4];
    const float* bq      = (const float*)d_in[5];
    const float* bk      = (const float*)d_in[6];
    const float* bv      = (const float*)d_in[7];
    const float* wo      = (const float*)d_in[8];
    const float* bo      = (const float*)d_in[9];
    const float* w_write = (const float*)d_in[10];
    const float* b_write = (const float*)d_in[11];
    const float* w_a1    = (const float*)d_in[12];
    const float* b_a1    = (const float*)d_in[13];
    const float* w_a2    = (const float*)d_in[14];
    const float* b_a2    = (const float*)d_in[15];
    float* out = (float*)d_out;

    actformer_kernel<<<dim3(BB), dim3(NT), 0, stream>>>(
        query, scratch, wq, wk, wv, bq, bk, bv, wo, bo,
        w_write, b_write, w_a1, b_a1, w_a2, b_a2, out);
}